// Round 3
// baseline (1521.461 us; speedup 1.0000x reference)
//
#include <hip/hip_runtime.h>

#define B_ 8
#define S_ 1025
#define E_ 768
#define H_ 12
#define D_ 64
#define N_ 1024
#define M_OUT (B_*S_)   // 8200

// ---------------- QKV projection: q/k/v = xt @ W^T + b, fp32 out -------------
// 128x128 tile, 8x8 micro, BK=16. M=8192 (xt rows skip the cls row per batch).
__global__ __launch_bounds__(256) void proj_qkv_kernel(
    const float* __restrict__ x,
    const float* __restrict__ Wq, const float* __restrict__ bq,
    const float* __restrict__ Wk, const float* __restrict__ bk,
    const float* __restrict__ Wv, const float* __restrict__ bv,
    float* __restrict__ qo, float* __restrict__ ko, float* __restrict__ vo)
{
  __shared__ float As[16][128];
  __shared__ float Bs[16][128];

  const int which = blockIdx.z;
  const float* __restrict__ W    = (which == 0) ? Wq : (which == 1) ? Wk : Wv;
  const float* __restrict__ bias = (which == 0) ? bq : (which == 1) ? bk : bv;
  float* __restrict__ out        = (which == 0) ? qo : (which == 1) ? ko : vo;

  const int tid = threadIdx.x;
  const int tx = tid & 15, ty = tid >> 4;
  const int m0 = blockIdx.y * 128;
  const int n0 = blockIdx.x * 128;

  const int lm = tid >> 1;        // 0..127: tile row staged by this thread
  const int lk = (tid & 1) * 8;   // 0 or 8: k-subchunk

  const int gm = m0 + lm;
  // xt row -> x row: b*S + 1 + i  ==  gm + (gm>>10) + 1   (n = 1024)
  const long arow = (long)(gm + (gm >> 10) + 1) * E_;
  const long brow = (long)(n0 + lm) * E_;

  float acc[8][8] = {};

  for (int k0 = 0; k0 < E_; k0 += 16) {
    float4 a0 = *(const float4*)&x[arow + k0 + lk];
    float4 a1 = *(const float4*)&x[arow + k0 + lk + 4];
    float4 b0 = *(const float4*)&W[brow + k0 + lk];
    float4 b1 = *(const float4*)&W[brow + k0 + lk + 4];
    __syncthreads();
    As[lk+0][lm] = a0.x; As[lk+1][lm] = a0.y; As[lk+2][lm] = a0.z; As[lk+3][lm] = a0.w;
    As[lk+4][lm] = a1.x; As[lk+5][lm] = a1.y; As[lk+6][lm] = a1.z; As[lk+7][lm] = a1.w;
    Bs[lk+0][lm] = b0.x; Bs[lk+1][lm] = b0.y; Bs[lk+2][lm] = b0.z; Bs[lk+3][lm] = b0.w;
    Bs[lk+4][lm] = b1.x; Bs[lk+5][lm] = b1.y; Bs[lk+6][lm] = b1.z; Bs[lk+7][lm] = b1.w;
    __syncthreads();
    #pragma unroll
    for (int kk = 0; kk < 16; ++kk) {
      float4 va0 = *(const float4*)&As[kk][ty*8];
      float4 va1 = *(const float4*)&As[kk][ty*8+4];
      float4 vb0 = *(const float4*)&Bs[kk][tx*8];
      float4 vb1 = *(const float4*)&Bs[kk][tx*8+4];
      float av[8] = {va0.x,va0.y,va0.z,va0.w,va1.x,va1.y,va1.z,va1.w};
      float bv[8] = {vb0.x,vb0.y,vb0.z,vb0.w,vb1.x,vb1.y,vb1.z,vb1.w};
      #pragma unroll
      for (int i = 0; i < 8; ++i)
        #pragma unroll
        for (int j = 0; j < 8; ++j)
          acc[i][j] = fmaf(av[i], bv[j], acc[i][j]);
    }
  }

  float4 bb0 = *(const float4*)&bias[n0 + tx*8];
  float4 bb1 = *(const float4*)&bias[n0 + tx*8 + 4];
  float bb[8] = {bb0.x,bb0.y,bb0.z,bb0.w,bb1.x,bb1.y,bb1.z,bb1.w};
  #pragma unroll
  for (int i = 0; i < 8; ++i) {
    const long row = m0 + ty*8 + i;
    float4 o0 = make_float4(acc[i][0]+bb[0], acc[i][1]+bb[1], acc[i][2]+bb[2], acc[i][3]+bb[3]);
    float4 o1 = make_float4(acc[i][4]+bb[4], acc[i][5]+bb[5], acc[i][6]+bb[6], acc[i][7]+bb[7]);
    *(float4*)&out[row*E_ + n0 + tx*8]     = o0;
    *(float4*)&out[row*E_ + n0 + tx*8 + 4] = o1;
  }
}

// ---------------- Output projection: out = vals @ Wo^T + bo, fp32 out --------
__global__ __launch_bounds__(256) void proj_out_kernel(
    const float* __restrict__ A, const float* __restrict__ W,
    const float* __restrict__ bias, float* __restrict__ out)
{
  __shared__ float As[16][128];
  __shared__ float Bs[16][128];

  const int tid = threadIdx.x;
  const int tx = tid & 15, ty = tid >> 4;
  const int m0 = blockIdx.y * 128;
  const int n0 = blockIdx.x * 128;

  const int lm = tid >> 1;
  const int lk = (tid & 1) * 8;

  const int gm = m0 + lm;
  const long brow = (long)(n0 + lm) * E_;

  float acc[8][8] = {};

  for (int k0 = 0; k0 < E_; k0 += 16) {
    float4 a0 = make_float4(0.f,0.f,0.f,0.f), a1 = make_float4(0.f,0.f,0.f,0.f);
    if (gm < M_OUT) {
      a0 = *(const float4*)&A[(long)gm*E_ + k0 + lk];
      a1 = *(const float4*)&A[(long)gm*E_ + k0 + lk + 4];
    }
    float4 b0 = *(const float4*)&W[brow + k0 + lk];
    float4 b1 = *(const float4*)&W[brow + k0 + lk + 4];
    __syncthreads();
    As[lk+0][lm] = a0.x; As[lk+1][lm] = a0.y; As[lk+2][lm] = a0.z; As[lk+3][lm] = a0.w;
    As[lk+4][lm] = a1.x; As[lk+5][lm] = a1.y; As[lk+6][lm] = a1.z; As[lk+7][lm] = a1.w;
    Bs[lk+0][lm] = b0.x; Bs[lk+1][lm] = b0.y; Bs[lk+2][lm] = b0.z; Bs[lk+3][lm] = b0.w;
    Bs[lk+4][lm] = b1.x; Bs[lk+5][lm] = b1.y; Bs[lk+6][lm] = b1.z; Bs[lk+7][lm] = b1.w;
    __syncthreads();
    #pragma unroll
    for (int kk = 0; kk < 16; ++kk) {
      float4 va0 = *(const float4*)&As[kk][ty*8];
      float4 va1 = *(const float4*)&As[kk][ty*8+4];
      float4 vb0 = *(const float4*)&Bs[kk][tx*8];
      float4 vb1 = *(const float4*)&Bs[kk][tx*8+4];
      float av[8] = {va0.x,va0.y,va0.z,va0.w,va1.x,va1.y,va1.z,va1.w};
      float bv[8] = {vb0.x,vb0.y,vb0.z,vb0.w,vb1.x,vb1.y,vb1.z,vb1.w};
      #pragma unroll
      for (int i = 0; i < 8; ++i)
        #pragma unroll
        for (int j = 0; j < 8; ++j)
          acc[i][j] = fmaf(av[i], bv[j], acc[i][j]);
    }
  }

  float4 bb0 = *(const float4*)&bias[n0 + tx*8];
  float4 bb1 = *(const float4*)&bias[n0 + tx*8 + 4];
  float bb[8] = {bb0.x,bb0.y,bb0.z,bb0.w,bb1.x,bb1.y,bb1.z,bb1.w};
  #pragma unroll
  for (int i = 0; i < 8; ++i) {
    const int row = m0 + ty*8 + i;
    if (row < M_OUT) {
      float4 o0 = make_float4(acc[i][0]+bb[0], acc[i][1]+bb[1], acc[i][2]+bb[2], acc[i][3]+bb[3]);
      float4 o1 = make_float4(acc[i][4]+bb[4], acc[i][5]+bb[5], acc[i][6]+bb[6], acc[i][7]+bb[7]);
      *(float4*)&out[(long)row*E_ + n0 + tx*8]     = o0;
      *(float4*)&out[(long)row*E_ + n0 + tx*8 + 4] = o1;
    }
  }
}

// ---------------- c = cls @ Wc^T + bc ; cdenom = 1/sqrt(D*clip(|c|^2)) -------
__global__ __launch_bounds__(64) void cls_c_kernel(
    const float* __restrict__ x, const float* __restrict__ Wc, const float* __restrict__ bc,
    float* __restrict__ cbuf, float* __restrict__ cdenom)
{
  const int bh = blockIdx.x;
  const int b = bh / H_, h = bh % H_;
  const int d = threadIdx.x;
  const float* xr = x + (long)b*S_*E_;          // cls row (token 0)
  const float* wr = Wc + (long)(h*D_ + d)*E_;
  float acc = 0.f;
  for (int j = 0; j < E_; j += 4) {
    float4 xw = *(const float4*)&xr[j];
    float4 ww = *(const float4*)&wr[j];
    acc += xw.x*ww.x + xw.y*ww.y + xw.z*ww.z + xw.w*ww.w;
  }
  acc += bc[h*D_ + d];
  cbuf[bh*D_ + d] = acc;
  float sq = acc*acc;
  #pragma unroll
  for (int off = 32; off > 0; off >>= 1) sq += __shfl_xor(sq, off);
  if (d == 0) cdenom[bh] = rsqrtf((float)D_ * fmaxf(sq, 1e-5f));
}

// ---------------- main attention: 64x64 tile per block -----------------------
// writes UNNORMALIZED exp(s) to attn (fp32), row sums to rowl_g, PV/l to vals
__global__ __launch_bounds__(256) void attn_kernel(
    const float* __restrict__ qbuf, const float* __restrict__ kbuf, const float* __restrict__ vbuf,
    const float* __restrict__ cbuf, const float* __restrict__ cdenom,
    float* __restrict__ vals, float* __restrict__ rowl_g, float* __restrict__ attn)
{
  __shared__ float qst[64][68];   // [d][q]  (transposed)
  __shared__ float kvs[64][68];   // first [d][k] (K transposed), then [k][d] (V natural)
  __shared__ float pst[64][68];   // [k][q]  (P transposed)
  __shared__ float cs[64];
  __shared__ float rowscale[64];
  __shared__ float rowl[64];

  const int qt = blockIdx.x, h = blockIdx.y, b = blockIdx.z;
  const int bh = b * H_ + h;
  const int q0 = qt * 64;
  const int tid = threadIdx.x;
  const int tx = tid & 15, ty = tid >> 4;
  const int lr = tid >> 2;          // staged row 0..63
  const int lc = (tid & 3) * 16;    // staged col chunk

  {
    const float* src = &qbuf[((long)b*N_ + q0 + lr)*E_ + h*D_ + lc];
    float4 t0 = *(const float4*)(src);
    float4 t1 = *(const float4*)(src+4);
    float4 t2 = *(const float4*)(src+8);
    float4 t3 = *(const float4*)(src+12);
    float tmp[16] = {t0.x,t0.y,t0.z,t0.w,t1.x,t1.y,t1.z,t1.w,
                     t2.x,t2.y,t2.z,t2.w,t3.x,t3.y,t3.z,t3.w};
    #pragma unroll
    for (int t = 0; t < 16; ++t) qst[lc+t][lr] = tmp[t];
  }
  if (tid < 64) cs[tid] = cbuf[bh*D_ + tid];
  const float cdn = cdenom[bh];
  __syncthreads();

  if (tid < 64) {
    const int r = tid;
    float qn2 = 0.f, cq = 0.f;
    #pragma unroll 8
    for (int d = 0; d < 64; ++d) {
      float qv = qst[d][r];
      qn2 = fmaf(qv, qv, qn2);
      cq  = fmaf(cs[d], qv, cq);
    }
    rowscale[r] = cq * cdn / fmaxf(qn2, 1e-5f);
    rowl[r] = 0.f;
  }

  float acc[4][4] = {};

  for (int kt = 0; kt < 16; ++kt) {
    __syncthreads();   // prev PV done; rowscale/rowl init visible on first iter
    {  // stage K transposed: kvs[d][k]
      const float* src = &kbuf[((long)b*N_ + kt*64 + lr)*E_ + h*D_ + lc];
      float4 t0 = *(const float4*)(src);
      float4 t1 = *(const float4*)(src+4);
      float4 t2 = *(const float4*)(src+8);
      float4 t3 = *(const float4*)(src+12);
      float tmp[16] = {t0.x,t0.y,t0.z,t0.w,t1.x,t1.y,t1.z,t1.w,
                       t2.x,t2.y,t2.z,t2.w,t3.x,t3.y,t3.z,t3.w};
      #pragma unroll
      for (int t = 0; t < 16; ++t) kvs[lc+t][lr] = tmp[t];
    }
    __syncthreads();

    float sacc[4][4] = {};
    #pragma unroll 8
    for (int d = 0; d < 64; ++d) {
      float4 a4 = *(const float4*)&qst[d][ty*4];
      float4 b4 = *(const float4*)&kvs[d][tx*4];
      float av[4] = {a4.x,a4.y,a4.z,a4.w};
      float bv[4] = {b4.x,b4.y,b4.z,b4.w};
      #pragma unroll
      for (int i = 0; i < 4; ++i)
        #pragma unroll
        for (int j = 0; j < 4; ++j)
          sacc[i][j] = fmaf(av[i], bv[j], sacc[i][j]);
    }
    #pragma unroll
    for (int i = 0; i < 4; ++i) {
      const int r = ty*4 + i;
      const float sc = rowscale[r];
      float p0 = __expf(fminf(sacc[i][0]*sc, 60.f));
      float p1 = __expf(fminf(sacc[i][1]*sc, 60.f));
      float p2 = __expf(fminf(sacc[i][2]*sc, 60.f));
      float p3 = __expf(fminf(sacc[i][3]*sc, 60.f));
      pst[tx*4+0][r] = p0;
      pst[tx*4+1][r] = p1;
      pst[tx*4+2][r] = p2;
      pst[tx*4+3][r] = p3;
      float ps = p0+p1+p2+p3;
      ps += __shfl_xor(ps, 1);
      ps += __shfl_xor(ps, 2);
      ps += __shfl_xor(ps, 4);
      ps += __shfl_xor(ps, 8);
      if (tx == 0) rowl[r] += ps;
      *(float4*)&attn[((long)(bh*N_ + q0 + r) << 10) + kt*64 + tx*4] =
          make_float4(p0, p1, p2, p3);
    }
    __syncthreads();
    {  // stage V natural: kvs[k][d]
      const float* src = &vbuf[((long)b*N_ + kt*64 + lr)*E_ + h*D_ + lc];
      float4 t0 = *(const float4*)(src);
      float4 t1 = *(const float4*)(src+4);
      float4 t2 = *(const float4*)(src+8);
      float4 t3 = *(const float4*)(src+12);
      *(float4*)&kvs[lr][lc]    = t0;
      *(float4*)&kvs[lr][lc+4]  = t1;
      *(float4*)&kvs[lr][lc+8]  = t2;
      *(float4*)&kvs[lr][lc+12] = t3;
    }
    __syncthreads();

    #pragma unroll 8
    for (int c = 0; c < 64; ++c) {
      float4 a4 = *(const float4*)&pst[c][ty*4];
      float4 b4 = *(const float4*)&kvs[c][tx*4];
      float av[4] = {a4.x,a4.y,a4.z,a4.w};
      float bv[4] = {b4.x,b4.y,b4.z,b4.w};
      #pragma unroll
      for (int i = 0; i < 4; ++i)
        #pragma unroll
        for (int j = 0; j < 4; ++j)
          acc[i][j] = fmaf(av[i], bv[j], acc[i][j]);
    }
  }
  __syncthreads();

  #pragma unroll
  for (int i = 0; i < 4; ++i) {
    const int r = ty*4 + i;
    const float inv = 1.0f / rowl[r];
    float4 o = make_float4(acc[i][0]*inv, acc[i][1]*inv, acc[i][2]*inv, acc[i][3]*inv);
    *(float4*)&vals[((long)b*S_ + 1 + q0 + r)*E_ + h*D_ + tx*4] = o;
  }
  if (tid < 64) rowl_g[(long)bh*N_ + q0 + tid] = rowl[tid];
}

// ---------------- CLS output row (no softmax) --------------------------------
__global__ __launch_bounds__(256) void cls_attn_kernel(
    const float* __restrict__ x, const float* __restrict__ kbuf, const float* __restrict__ vbuf,
    const float* __restrict__ cbuf, const float* __restrict__ cdenom, float* __restrict__ vals)
{
  __shared__ float cs[64];
  __shared__ float part[4][64];
  const int bh = blockIdx.x;
  const int b = bh / H_, h = bh % H_;
  const int tid = threadIdx.x;
  const int wv = tid >> 6, lane = tid & 63;
  if (tid < 64) cs[tid] = cbuf[bh*D_ + tid];
  __syncthreads();
  float acc = 0.f;
  const long base0 = (long)b*N_*E_ + h*D_ + lane;
  for (int kk = wv*256; kk < wv*256 + 256; ++kk) {
    const long base = base0 + (long)kk*E_;
    float s = cs[lane] * kbuf[base];
    s += __shfl_xor(s, 1);  s += __shfl_xor(s, 2);  s += __shfl_xor(s, 4);
    s += __shfl_xor(s, 8);  s += __shfl_xor(s, 16); s += __shfl_xor(s, 32);
    acc = fmaf(s, vbuf[base], acc);
  }
  part[wv][lane] = acc;
  __syncthreads();
  if (tid < 64) {
    const float tot = (part[0][tid] + part[1][tid] + part[2][tid] + part[3][tid]) * cdenom[bh];
    const float cls = x[(long)b*S_*E_ + h*D_ + tid];
    vals[(long)b*S_*E_ + h*D_ + tid] = (cls + tot) * 0.5f;
  }
}

// ---------------- normalize stored attn in place (fp32) ----------------------
__global__ __launch_bounds__(256) void rescale_kernel(
    float* __restrict__ attn, const float* __restrict__ rowl_g)
{
  const long row = blockIdx.x;
  const float inv = 1.0f / rowl_g[row];
  float* p = attn + (row << 10) + threadIdx.x * 4;
  float4 u = *(float4*)p;
  u.x *= inv; u.y *= inv; u.z *= inv; u.w *= inv;
  *(float4*)p = u;
}

extern "C" void kernel_launch(void* const* d_in, const int* in_sizes, int n_in,
                              void* d_out, int out_size, void* d_ws, size_t ws_size,
                              hipStream_t stream) {
  (void)in_sizes; (void)n_in; (void)out_size; (void)ws_size;
  const float* x  = (const float*)d_in[0];
  const float* Wq = (const float*)d_in[1];
  const float* bq = (const float*)d_in[2];
  const float* Wk = (const float*)d_in[3];
  const float* bk = (const float*)d_in[4];
  const float* Wv = (const float*)d_in[5];
  const float* bv = (const float*)d_in[6];
  const float* Wc = (const float*)d_in[7];
  const float* bc = (const float*)d_in[8];
  const float* Wo = (const float*)d_in[9];
  const float* bo = (const float*)d_in[10];

  float* outp = (float*)d_out;
  float* attn = outp + (long)B_*S_*E_;   // fp32 outputs, concatenated flat

  // workspace (fp32): q,k,v (B*N*E each), vals (B*S*E), c, cdenom, rowl  ~101 MiB
  float* qb   = (float*)d_ws;
  float* kb   = qb + (long)B_*N_*E_;
  float* vb   = kb + (long)B_*N_*E_;
  float* vals = vb + (long)B_*N_*E_;
  float* cbuf = vals + (long)B_*S_*E_;
  float* cden = cbuf + B_*H_*D_;
  float* rowl = cden + B_*H_;

  proj_qkv_kernel<<<dim3(6, 64, 3), 256, 0, stream>>>(x, Wq, bq, Wk, bk, Wv, bv, qb, kb, vb);
  cls_c_kernel<<<B_*H_, 64, 0, stream>>>(x, Wc, bc, cbuf, cden);
  attn_kernel<<<dim3(16, H_, B_), 256, 0, stream>>>(qb, kb, vb, cbuf, cden, vals, rowl, attn);
  cls_attn_kernel<<<B_*H_, 256, 0, stream>>>(x, kb, vb, cbuf, cden, vals);
  rescale_kernel<<<B_*H_*N_, 256, 0, stream>>>(attn, rowl);
  proj_out_kernel<<<dim3(6, 65), 256, 0, stream>>>(vals, Wo, bo, outp);
}